// Round 8
// baseline (919.114 us; speedup 1.0000x reference)
//
#include <hip/hip_runtime.h>
#include <math.h>

#define N_NODES 40000
#define M_PAD   40064          // 313 * 128
#define N_EDGES 640000
#define ETOT    (N_EDGES + N_NODES)
#define DINC    512            // DIN == H*C
#define NHEAD   4
#define CHD     128
#define BN_EPS  1e-5f

typedef __attribute__((ext_vector_type(8))) short bf16x8;
typedef __attribute__((ext_vector_type(4))) float f32x4;

static __device__ __forceinline__ float lrelu(float x) { return x > 0.f ? x : 0.2f * x; }

static __device__ __forceinline__ unsigned short f2b(float f) {
    union { float f; unsigned int u; } v; v.f = f;
    unsigned int r = (v.u + 0x7fff + ((v.u >> 16) & 1)) >> 16;
    return (unsigned short)r;
}
static __device__ __forceinline__ float b2f(unsigned short b) {
    union { unsigned int u; float f; } v; v.u = ((unsigned int)b) << 16;
    return v.f;
}
static __device__ __forceinline__ float lo16(unsigned int u) {
    union { unsigned int u; float f; } v; v.u = u << 16; return v.f;
}
static __device__ __forceinline__ float hi16(unsigned int u) {
    union { unsigned int u; float f; } v; v.u = u & 0xffff0000u; return v.f;
}

// 8-channel bf16 FMA into f32 accumulators (inline fn, not macro)
static __device__ __forceinline__ void fma8(float* acc, uint4 hv, float wgt) {
    acc[0] += wgt * lo16(hv.x); acc[1] += wgt * hi16(hv.x);
    acc[2] += wgt * lo16(hv.y); acc[3] += wgt * hi16(hv.y);
    acc[4] += wgt * lo16(hv.z); acc[5] += wgt * hi16(hv.z);
    acc[6] += wgt * lo16(hv.w); acc[7] += wgt * hi16(hv.w);
}

#define GLDS16(g, l) __builtin_amdgcn_global_load_lds( \
    (__attribute__((address_space(1))) void*)(g),      \
    (__attribute__((address_space(3))) void*)(l), 16, 0, 0)

// ---------------- prep: x->bf16, zero pads, zero cnt (one kernel) ----------------
#define CVTX_BLK 10000
__global__ __launch_bounds__(256) void k_prep(const float4* __restrict__ xin,
                                              uint4* __restrict__ xb,
                                              uint4* __restrict__ curb,
                                              uint4* __restrict__ cnt4) {
    int bid = blockIdx.x;
    int tid = threadIdx.x;
    if (bid < CVTX_BLK) {
        size_t i = (size_t)bid * 256 + tid;
        float4 a = xin[i * 2], b = xin[i * 2 + 1];
        uint4 o;
        o.x = (unsigned)f2b(a.x) | ((unsigned)f2b(a.y) << 16);
        o.y = (unsigned)f2b(a.z) | ((unsigned)f2b(a.w) << 16);
        o.z = (unsigned)f2b(b.x) | ((unsigned)f2b(b.y) << 16);
        o.w = (unsigned)f2b(b.z) | ((unsigned)f2b(b.w) << 16);
        xb[i] = o;
    } else if (bid < CVTX_BLK + 16) {
        int i = (bid - CVTX_BLK) * 256 + tid;     // < 4096
        xb[(size_t)N_NODES * DINC / 8 + i] = make_uint4(0, 0, 0, 0);
    } else if (bid < CVTX_BLK + 32) {
        int i = (bid - CVTX_BLK - 16) * 256 + tid;
        curb[(size_t)N_NODES * DINC / 8 + i] = make_uint4(0, 0, 0, 0);
    } else {
        int i = (bid - CVTX_BLK - 32) * 256 + tid;
        if (i < N_NODES / 4) cnt4[i] = make_uint4(0, 0, 0, 0);
    }
}

// ---------------- all weight conversions (one kernel) ----------------
// W [K][Nn] f32 -> Wt [Nn][K] bf16, 5 jobs concatenated
__global__ __launch_bounds__(256) void k_cvtw_all(const float* __restrict__ W1, unsigned short* __restrict__ T1,
                                                  const float* __restrict__ W2, unsigned short* __restrict__ T2,
                                                  const float* __restrict__ W3, unsigned short* __restrict__ T3,
                                                  const float* __restrict__ Wg1, const float* __restrict__ Wf1,
                                                  unsigned short* __restrict__ Wct) {
    int idx = blockIdx.x * 256 + threadIdx.x;
    const float* W; unsigned short* T; int Nn;
    if (idx < 262144)            { W = W1; T = T1; Nn = 512; }
    else if (idx < 524288)       { W = W2; T = T2; Nn = 512; idx -= 262144; }
    else if (idx < 786432)       { W = W3; T = T3; Nn = 512; idx -= 524288; }
    else if (idx < 851968)       { W = Wg1; T = Wct; Nn = 128; idx -= 786432; }
    else                         { W = Wf1; T = Wct + 65536; Nn = 128; idx -= 851968; }
    int k = idx / Nn, n = idx % Nn;
    T[(size_t)n * 512 + k] = f2b(W[idx]);
}

// ---------------- CSR build ----------------
__global__ void k_degree(const int* __restrict__ ei, int* __restrict__ cnt) {
    int e = blockIdx.x * 256 + threadIdx.x;
    if (e < ETOT) {
        int dst = (e < N_EDGES) ? ei[N_EDGES + e] : (e - N_EDGES);
        atomicAdd(&cnt[dst], 1);
    }
}

__global__ __launch_bounds__(64) void k_scan1(const int* __restrict__ deg, int* __restrict__ bsum) {
    int lane = threadIdx.x;
    int v = deg[blockIdx.x * 64 + lane];
#pragma unroll
    for (int off = 32; off; off >>= 1) v += __shfl_xor(v, off);
    if (lane == 0) bsum[blockIdx.x] = v;
}

// fused scan2+scan3: block b computes its global prefix from bsum, then local
// wave scan of its 64 degrees; also re-zeroes cnt for k_fill.
__global__ __launch_bounds__(64) void k_scan23(const int* __restrict__ deg, const int* __restrict__ bsum,
                                               int* __restrict__ rowptr, int* __restrict__ cnt) {
    int b = blockIdx.x, lane = threadIdx.x;
    int pre = 0;
    for (int i = lane; i < b; i += 64) pre += bsum[i];
#pragma unroll
    for (int off = 32; off; off >>= 1) pre += __shfl_xor(pre, off);
    int i = b * 64 + lane;
    int v = deg[i];
    int inc = v;
#pragma unroll
    for (int off = 1; off < 64; off <<= 1) {
        int t = __shfl_up(inc, off);
        if (lane >= off) inc += t;
    }
    rowptr[i] = pre + inc - v;
    cnt[i] = 0;
    if (b == 624 && lane == 63) rowptr[N_NODES] = ETOT;
}

__global__ void k_fill(const int* __restrict__ ei, const int* __restrict__ rowptr,
                       int* __restrict__ cnt, int* __restrict__ csr_src) {
    int e = blockIdx.x * 256 + threadIdx.x;
    if (e < ETOT) {
        int src, dst;
        if (e < N_EDGES) { src = ei[e]; dst = ei[N_EDGES + e]; }
        else             { src = e - N_EDGES; dst = src; }
        int pos = rowptr[dst] + atomicAdd(&cnt[dst], 1);
        csr_src[pos] = src;
    }
}

// ---------------- bf16 MFMA GEMM + fused epilogues ----------------
// EPI=1: per-layer es/ed epilogue. EPI=2: scores(G half)/relu-F(F half).
template<int CBF16, int EPI>
__global__ __launch_bounds__(256) void k_gemm_mfma(const unsigned short* __restrict__ A,
                                                   const unsigned short* __restrict__ Bt,
                                                   void* __restrict__ Cout,
                                                   int Nn, int K, int nbn,
                                                   const float* __restrict__ p1,   // as_ | bg1
                                                   const float* __restrict__ p2,   // ad_ | Wg2
                                                   float* __restrict__ p3,         // es  | scores
                                                   float* __restrict__ p4,         // ed  | Fb
                                                   const float* __restrict__ p5,   // -   | bg2
                                                   const float* __restrict__ p6) { // -   | bf1
    __shared__ alignas(16) unsigned short As[128 * 64];
    __shared__ alignas(16) unsigned short Bs[128 * 64];
    const int tid  = threadIdx.x;
    const int wv   = tid >> 6;
    const int lane = tid & 63;
    const int bm = (blockIdx.x / nbn) * 128;
    const int bn = (blockIdx.x % nbn) * 128;
    const int wm = (wv >> 1) * 64;
    const int wn = (wv & 1) * 64;

    const int srow = lane >> 3;
    const int scol = (((lane & 7) ^ srow) * 8);
    const size_t a_base = (size_t)(bm + wv * 32 + srow) * K + scol;
    const size_t b_base = (size_t)(bn + wv * 32 + srow) * K + scol;

    f32x4 acc[4][4] = {};

    for (int k0 = 0; k0 < K; k0 += 64) {
#pragma unroll
        for (int q = 0; q < 4; ++q)
            GLDS16(A + a_base + (size_t)q * 8 * K + k0, &As[(wv * 32 + q * 8) * 64]);
#pragma unroll
        for (int q = 0; q < 4; ++q)
            GLDS16(Bt + b_base + (size_t)q * 8 * K + k0, &Bs[(wv * 32 + q * 8) * 64]);
        __syncthreads();

        const int r0 = lane & 15;
#pragma unroll
        for (int ks = 0; ks < 2; ++ks) {
            const int c = ks * 4 + (lane >> 4);
            bf16x8 af[4], bfr[4];
#pragma unroll
            for (int i = 0; i < 4; ++i) {
                int row = wm + i * 16 + r0;
                af[i] = *(const bf16x8*)&As[row * 64 + ((c ^ (row & 7)) * 8)];
            }
#pragma unroll
            for (int j = 0; j < 4; ++j) {
                int row = wn + j * 16 + r0;
                bfr[j] = *(const bf16x8*)&Bs[row * 64 + ((c ^ (row & 7)) * 8)];
            }
#pragma unroll
            for (int i = 0; i < 4; ++i)
#pragma unroll
                for (int j = 0; j < 4; ++j)
                    acc[i][j] = __builtin_amdgcn_mfma_f32_16x16x32_bf16(af[i], bfr[j], acc[i][j], 0, 0, 0);
        }
        __syncthreads();
    }

    const int crow0 = bm + wm + (lane >> 4) * 4;
    const int ccol  = bn + wn + (lane & 15);

    if (EPI != 2) {
#pragma unroll
        for (int i = 0; i < 4; ++i)
#pragma unroll
            for (int j = 0; j < 4; ++j)
#pragma unroll
                for (int r = 0; r < 4; ++r) {
                    size_t off = (size_t)(crow0 + i * 16 + r) * Nn + ccol + j * 16;
                    if (CBF16) ((unsigned short*)Cout)[off] = f2b(acc[i][j][r]);
                    else       ((float*)Cout)[off] = acc[i][j][r];
                }
    }

    if (EPI == 1) {
        // block covers cols [bn, bn+128) == head bn>>7 entirely -> full es/ed rows
        const int head = bn >> 7;
        float asv[4], adv[4];
#pragma unroll
        for (int j = 0; j < 4; ++j) {
            int cc = head * CHD + wn + j * 16 + (lane & 15);
            asv[j] = p1[cc];
            adv[j] = p2[cc];
        }
        float* sE = (float*)As;          // reuse LDS: 128 es + 128 ed
        sE[tid] = 0.f;
        __syncthreads();
#pragma unroll
        for (int i = 0; i < 4; ++i)
#pragma unroll
            for (int r = 0; r < 4; ++r) {
                float e = acc[i][0][r] * asv[0] + acc[i][1][r] * asv[1]
                        + acc[i][2][r] * asv[2] + acc[i][3][r] * asv[3];
                float d = acc[i][0][r] * adv[0] + acc[i][1][r] * adv[1]
                        + acc[i][2][r] * adv[2] + acc[i][3][r] * adv[3];
#pragma unroll
                for (int off = 8; off; off >>= 1) {
                    e += __shfl_xor(e, off);
                    d += __shfl_xor(d, off);
                }
                if ((lane & 15) == 0) {
                    int rloc = wm + i * 16 + (lane >> 4) * 4 + r;
                    atomicAdd(&sE[rloc], e);
                    atomicAdd(&sE[128 + rloc], d);
                }
            }
        __syncthreads();
        if (tid < 128) {
            p3[(size_t)(bm + tid) * NHEAD + head] = sE[tid];
            p4[(size_t)(bm + tid) * NHEAD + head] = sE[128 + tid];
        }
    }

    if (EPI == 2) {
        if (bn == 0) {
            // G half: score[row] = sum_col tanh(g+bg1)*Wg2 + bg2
            float wgv[4], bgv[4];
#pragma unroll
            for (int j = 0; j < 4; ++j) {
                int cc = wn + j * 16 + (lane & 15);
                bgv[j] = p1[cc];
                wgv[j] = p2[cc];
            }
            float* sE = (float*)As;
            sE[tid] = 0.f;
            __syncthreads();
#pragma unroll
            for (int i = 0; i < 4; ++i)
#pragma unroll
                for (int r = 0; r < 4; ++r) {
                    float e = tanhf(acc[i][0][r] + bgv[0]) * wgv[0]
                            + tanhf(acc[i][1][r] + bgv[1]) * wgv[1]
                            + tanhf(acc[i][2][r] + bgv[2]) * wgv[2]
                            + tanhf(acc[i][3][r] + bgv[3]) * wgv[3];
#pragma unroll
                    for (int off = 8; off; off >>= 1) e += __shfl_xor(e, off);
                    if ((lane & 15) == 0)
                        atomicAdd(&sE[wm + i * 16 + (lane >> 4) * 4 + r], e);
                }
            __syncthreads();
            if (tid < 128) p3[bm + tid] = sE[tid] + p5[0];
        } else {
            // F half: Fb[row][col] = relu(f + bf1[col])
#pragma unroll
            for (int j = 0; j < 4; ++j) {
                int colF = wn + j * 16 + (lane & 15);
                float bv = p6[colF];
#pragma unroll
                for (int i = 0; i < 4; ++i)
#pragma unroll
                    for (int r = 0; r < 4; ++r)
                        p4[(size_t)(crow0 + i * 16 + r) * 128 + colF] =
                            fmaxf(acc[i][j][r] + bv, 0.f);
            }
        }
    }
}

// ---------------- fused softmax-weights + aggregate: block/node ----------------
// Prologue: all 256 threads gather es for this node's edges in parallel (high
// MLP -- this is what r6's inline version lacked), compute ex=exp(lrelu(es+ed))
// once per edge (softmax is shift-invariant; |e| <~ 6 so no max subtraction
// needed), stash in LDS, LDS-atomic the per-head sum. FMA loop = r7's proven
// 2-deep prefetch structure with weights read (broadcast) from LDS; normalize
// once at the end by 1/sum. Block 0 also zeroes BN stats for this layer.
__global__ __launch_bounds__(256) void k_agg(const unsigned short* __restrict__ hb,
                                             const float4* __restrict__ es4,
                                             const float4* __restrict__ ed4,
                                             const int* __restrict__ rowptr,
                                             const int* __restrict__ csr_src,
                                             unsigned short* __restrict__ aggb,
                                             float* __restrict__ stats) {
    __shared__ float part[4][512];
    __shared__ float4 s_w[256];
    __shared__ int s_src[256];
    __shared__ float s_sum[4];
    const int n = blockIdx.x;
    const int tid = threadIdx.x;
    const int grp = tid >> 6;
    const int lane = tid & 63;
    const int head = lane >> 4;
    const int start = rowptr[n], end = rowptr[n + 1];

    if (n == 0)
        for (int q = tid; q < DINC * 2; q += 256) stats[q] = 0.f;
    if (tid < 4) s_sum[tid] = 1e-16f;
    const float4 edn = ed4[n];

    float acc[8] = {};
    for (int base = start; base < end; base += 256) {
        const int cnt = min(256, end - base);
        __syncthreads();                       // s_sum init / s_w reuse safe
        if (tid < cnt) {
            int s = csr_src[base + tid];
            s_src[tid] = s;
            float4 e = es4[s];
            float4 ex;
            ex.x = __expf(lrelu(e.x + edn.x));
            ex.y = __expf(lrelu(e.y + edn.y));
            ex.z = __expf(lrelu(e.z + edn.z));
            ex.w = __expf(lrelu(e.w + edn.w));
            s_w[tid] = ex;
            atomicAdd(&s_sum[0], ex.x);
            atomicAdd(&s_sum[1], ex.y);
            atomicAdd(&s_sum[2], ex.z);
            atomicAdd(&s_sum[3], ex.w);
        }
        __syncthreads();
        // proven 2-deep-prefetch FMA loop; group grp takes every 4th edge
        int i = grp;
        int s_n = 0; float w_n = 0.f;
        if (i < cnt) { s_n = s_src[i]; w_n = ((const float*)&s_w[i])[head]; }
        while (i < cnt) {
            int s = s_n; float wgt = w_n;
            int i2 = i + 4;
            if (i2 < cnt) { s_n = s_src[i2]; w_n = ((const float*)&s_w[i2])[head]; }
            uint4 hv = *(const uint4*)&hb[(size_t)s * DINC + lane * 8];
            fma8(acc, hv, wgt);
            i = i2;
        }
    }
    *(float4*)&part[grp][lane * 8]     = make_float4(acc[0], acc[1], acc[2], acc[3]);
    *(float4*)&part[grp][lane * 8 + 4] = make_float4(acc[4], acc[5], acc[6], acc[7]);
    __syncthreads();
    const int c = tid * 2;
    float v0 = part[0][c] + part[1][c] + part[2][c] + part[3][c];
    float v1 = part[0][c + 1] + part[1][c + 1] + part[2][c + 1] + part[3][c + 1];
    float iv = 1.f / s_sum[tid >> 6];
    v0 *= iv; v1 *= iv;
    unsigned int o = (unsigned)f2b(v0) | ((unsigned)f2b(v1) << 16);
    *(unsigned int*)&aggb[(size_t)n * DINC + c] = o;
}

// ---------------- BatchNorm (bf16 agg) ----------------
__global__ __launch_bounds__(256) void k_bn_stats(const unsigned short* __restrict__ aggb,
                                                  float* __restrict__ stats) {
    int tid = threadIdx.x;
    int row0 = blockIdx.x * 64;
    int c0 = tid * 2;
    float s0 = 0, q0 = 0, s1 = 0, q1 = 0;
    for (int r = row0; r < row0 + 64; ++r) {
        unsigned int hv = *(const unsigned int*)&aggb[(size_t)r * DINC + c0];
        float v0 = lo16(hv), v1 = hi16(hv);
        s0 += v0; q0 += v0 * v0;
        s1 += v1; q1 += v1 * v1;
    }
    atomicAdd(&stats[c0], s0);
    atomicAdd(&stats[c0 + 1], s1);
    atomicAdd(&stats[DINC + c0], q0);
    atomicAdd(&stats[DINC + c0 + 1], q1);
}

// bn_act with fused bn_fin: each thread derives A,B for its 8 channels from stats
__global__ __launch_bounds__(256) void k_bn_act(const unsigned short* __restrict__ aggb,
                                                const float* __restrict__ stats,
                                                const float* __restrict__ g,
                                                const float* __restrict__ be,
                                                unsigned short* __restrict__ curb,
                                                int res) {
    size_t idx = (size_t)blockIdx.x * 256 + threadIdx.x;   // < N*64, 8 ch each
    int c8 = ((int)(idx & 63)) * 8;
    uint4 v = *(const uint4*)&aggb[idx * 8];
    float xv[8] = { lo16(v.x), hi16(v.x), lo16(v.y), hi16(v.y),
                    lo16(v.z), hi16(v.z), lo16(v.w), hi16(v.w) };
#pragma unroll
    for (int q = 0; q < 8; ++q) {
        int c = c8 + q;
        float mu = stats[c] * (1.f / N_NODES);
        float var = stats[DINC + c] * (1.f / N_NODES) - mu * mu;
        float A = g[c] * rsqrtf(var + BN_EPS);
        float B = be[c] - mu * A;
        xv[q] = lrelu(xv[q] * A + B);
    }
    if (res) {
        uint4 r = *(const uint4*)&curb[idx * 8];
        xv[0] += lo16(r.x); xv[1] += hi16(r.x);
        xv[2] += lo16(r.y); xv[3] += hi16(r.y);
        xv[4] += lo16(r.z); xv[5] += hi16(r.z);
        xv[6] += lo16(r.w); xv[7] += hi16(r.w);
    }
    uint4 o;
    o.x = (unsigned)f2b(xv[0]) | ((unsigned)f2b(xv[1]) << 16);
    o.y = (unsigned)f2b(xv[2]) | ((unsigned)f2b(xv[3]) << 16);
    o.z = (unsigned)f2b(xv[4]) | ((unsigned)f2b(xv[5]) << 16);
    o.w = (unsigned)f2b(xv[6]) | ((unsigned)f2b(xv[7]) << 16);
    *(uint4*)&curb[idx * 8] = o;
}

// ---------------- epilogue ----------------
__global__ __launch_bounds__(1024) void k_softmax(const float* __restrict__ scores, float* __restrict__ sm,
                                                  float* __restrict__ vbuf, float* __restrict__ pooled) {
    __shared__ float red[16];
    int tid = threadIdx.x, lane = tid & 63, wv = tid >> 6;
    if (tid < 128) vbuf[tid] = 0.f;
    if (tid < DINC) pooled[tid] = 0.f;
    float m = -1e30f;
    for (int i = tid; i < N_NODES; i += 1024) m = fmaxf(m, scores[i]);
#pragma unroll
    for (int off = 32; off; off >>= 1) m = fmaxf(m, __shfl_xor(m, off));
    if (lane == 0) red[wv] = m;
    __syncthreads();
    float mall = red[0];
    for (int i = 1; i < 16; ++i) mall = fmaxf(mall, red[i]);
    __syncthreads();
    float s = 0.f;
    for (int i = tid; i < N_NODES; i += 1024) s += expf(scores[i] - mall);
#pragma unroll
    for (int off = 32; off; off >>= 1) s += __shfl_xor(s, off);
    if (lane == 0) red[wv] = s;
    __syncthreads();
    if (tid == 0) {
        float tot = 0.f;
        for (int i = 0; i < 16; ++i) tot += red[i];
        sm[0] = mall; sm[1] = tot;
    }
}

__global__ __launch_bounds__(384) void k_vpool(const float* __restrict__ Fb,
                                               const unsigned short* __restrict__ hb,
                                               const float* __restrict__ scores,
                                               const float* __restrict__ sm,
                                               float* __restrict__ v,
                                               float* __restrict__ pooled) {
    int tid = threadIdx.x;
    int row0 = blockIdx.x * 64;
    float mall = sm[0];
    float invS = 1.f / sm[1];
    if (tid < 128) {
        float acc = 0.f;
        for (int r = row0; r < row0 + 64; ++r) {
            float w = expf(scores[r] - mall) * invS;
            acc += w * Fb[(size_t)r * 128 + tid];
        }
        atomicAdd(&v[tid], acc);
    } else {
        int c = (tid - 128) * 2;
        float a0 = 0.f, a1 = 0.f;
        for (int r = row0; r < row0 + 64; ++r) {
            unsigned int hv = *(const unsigned int*)&hb[(size_t)r * DINC + c];
            a0 += lo16(hv); a1 += hi16(hv);
        }
        atomicAdd(&pooled[c], a0 * (1.f / N_NODES));
        atomicAdd(&pooled[c + 1], a1 * (1.f / N_NODES));
    }
}

__global__ __launch_bounds__(128) void k_final(const float* __restrict__ v,
                                               const float* __restrict__ pooled,
                                               const float* __restrict__ Wf2,
                                               const float* __restrict__ bf2,
                                               const float* __restrict__ Wp,
                                               const float* __restrict__ bp,
                                               float* __restrict__ out) {
    __shared__ float sg[128];
    int o = threadIdx.x;
    float g = bf2[o];
    for (int k = 0; k < 128; ++k) g += v[k] * Wf2[k * 128 + o];
    sg[o] = g;
    __syncthreads();
    float acc = bp[o];
    for (int c = 0; c < 128; ++c) acc += sg[c] * Wp[c * 128 + o];
    for (int j = 0; j < 512; ++j) acc += pooled[j] * Wp[(128 + j) * 128 + o];
    out[o] = acc;
}

// ---------------- host launch ----------------
extern "C" void kernel_launch(void* const* d_in, const int* in_sizes, int n_in,
                              void* d_out, int out_size, void* d_ws, size_t ws_size,
                              hipStream_t stream) {
    const float* x  = (const float*)d_in[0];
    const int*   ei = (const int*)d_in[1];
    const float* Wg1 = (const float*)d_in[20];
    const float* bg1 = (const float*)d_in[21];
    const float* Wg2 = (const float*)d_in[22];
    const float* bg2 = (const float*)d_in[23];
    const float* Wf1 = (const float*)d_in[24];
    const float* bf1 = (const float*)d_in[25];
    const float* Wf2 = (const float*)d_in[26];
    const float* bf2 = (const float*)d_in[27];
    const float* Wp  = (const float*)d_in[28];
    const float* bp  = (const float*)d_in[29];
    float* out = (float*)d_out;

    char* base = (char*)d_ws;
    size_t off = 0;
    auto take = [&](size_t nbytes) -> char* {
        char* p = base + off;
        off += (nbytes + 255) & ~(size_t)255;
        return p;
    };
    unsigned short* hb   = (unsigned short*)take((size_t)M_PAD * DINC * 2);
    unsigned short* curb = (unsigned short*)take((size_t)M_PAD * DINC * 2);
    unsigned short* xb   = (unsigned short*)take((size_t)M_PAD * DINC * 2);
    unsigned short* aggb = (unsigned short*)take((size_t)M_PAD * DINC * 2);
    float* Fb    = (float*)take((size_t)M_PAD * 128 * 4);
    float* es    = (float*)take((size_t)M_PAD * NHEAD * 4);
    float* ed    = (float*)take((size_t)M_PAD * NHEAD * 4);
    int*   rowptr= (int*)take((size_t)(N_NODES + 1) * 4);
    int*   cnt   = (int*)take((size_t)N_NODES * 4);
    int*   csr   = (int*)take((size_t)ETOT * 4);
    int*   bsum  = (int*)take(625 * 4);
    float* stats = (float*)take(DINC * 2 * 4);
    float* sm    = (float*)take(2 * 4);
    float* vbuf  = (float*)take(128 * 4);
    float* pooled= (float*)take(DINC * 4);
    unsigned short* Wt1  = (unsigned short*)take((size_t)DINC * DINC * 2);
    unsigned short* Wt2  = (unsigned short*)take((size_t)DINC * DINC * 2);
    unsigned short* Wt3  = (unsigned short*)take((size_t)DINC * DINC * 2);
    unsigned short* Wct  = (unsigned short*)take((size_t)256 * DINC * 2);

    // prep + conversions + CSR build
    k_prep<<<CVTX_BLK + 32 + 40, 256, 0, stream>>>((const float4*)x, (uint4*)xb,
                                                   (uint4*)curb, (uint4*)cnt);
    k_cvtw_all<<<3584, 256, 0, stream>>>((const float*)d_in[2], Wt1,
                                         (const float*)d_in[8], Wt2,
                                         (const float*)d_in[14], Wt3,
                                         Wg1, Wf1, Wct);
    k_degree<<<(ETOT + 255) / 256, 256, 0, stream>>>(ei, cnt);
    k_scan1<<<625, 64, 0, stream>>>(cnt, bsum);
    k_scan23<<<625, 64, 0, stream>>>(cnt, bsum, rowptr, cnt);
    k_fill<<<(ETOT + 255) / 256, 256, 0, stream>>>(ei, rowptr, cnt, csr);

    const unsigned short* Wts[3] = {Wt1, Wt2, Wt3};
    const unsigned short* in = xb;
    for (int l = 0; l < 3; ++l) {
        const float* as_ = (const float*)d_in[2 + l * 6 + 1];
        const float* ad_ = (const float*)d_in[2 + l * 6 + 2];
        const float* g   = (const float*)d_in[2 + l * 6 + 4];
        const float* be  = (const float*)d_in[2 + l * 6 + 5];

        k_gemm_mfma<1, 1><<<(M_PAD / 128) * (DINC / 128), 256, 0, stream>>>(
            in, Wts[l], hb, DINC, DINC, DINC / 128, as_, ad_, es, ed, nullptr, nullptr);
        k_agg<<<N_NODES, 256, 0, stream>>>(hb, (const float4*)es, (const float4*)ed,
                                           rowptr, csr, aggb, stats);
        k_bn_stats<<<N_NODES / 64, 256, 0, stream>>>(aggb, stats);
        k_bn_act<<<(N_NODES * (DINC / 8)) / 256, 256, 0, stream>>>(aggb, stats, g, be, curb, l > 0 ? 1 : 0);
        in = curb;
    }

    // fused epilogue GEMM: [M,512] @ [512,256]; G half -> scores, F half -> relu F
    float* scores = out + 128;
    k_gemm_mfma<0, 2><<<(M_PAD / 128) * 2, 256, 0, stream>>>(
        curb, Wct, nullptr, 256, DINC, 2, bg1, Wg2, scores, Fb, bg2, bf1);

    k_softmax<<<1, 1024, 0, stream>>>(scores, sm, vbuf, pooled);
    k_vpool<<<N_NODES / 64, 384, 0, stream>>>(Fb, curb, scores, sm, vbuf, pooled);
    k_final<<<1, 128, 0, stream>>>(vbuf, pooled, Wf2, bf2, Wp, bp, out);
}

// Round 9
// 879.872 us; speedup vs baseline: 1.0446x; 1.0446x over previous
//
#include <hip/hip_runtime.h>
#include <math.h>

#define N_NODES 40000
#define M_PAD   40064          // 313 * 128
#define N_EDGES 640000
#define ETOT    (N_EDGES + N_NODES)
#define DINC    512            // DIN == H*C
#define NHEAD   4
#define CHD     128
#define BN_EPS  1e-5f

typedef __attribute__((ext_vector_type(8))) short bf16x8;
typedef __attribute__((ext_vector_type(4))) float f32x4;

static __device__ __forceinline__ float lrelu(float x) { return x > 0.f ? x : 0.2f * x; }

static __device__ __forceinline__ unsigned short f2b(float f) {
    union { float f; unsigned int u; } v; v.f = f;
    unsigned int r = (v.u + 0x7fff + ((v.u >> 16) & 1)) >> 16;
    return (unsigned short)r;
}
static __device__ __forceinline__ float b2f(unsigned short b) {
    union { unsigned int u; float f; } v; v.u = ((unsigned int)b) << 16;
    return v.f;
}
static __device__ __forceinline__ float lo16(unsigned int u) {
    union { unsigned int u; float f; } v; v.u = u << 16; return v.f;
}
static __device__ __forceinline__ float hi16(unsigned int u) {
    union { unsigned int u; float f; } v; v.u = u & 0xffff0000u; return v.f;
}

// 8-channel bf16 FMA into f32 accumulators (inline fn, not macro)
static __device__ __forceinline__ void fma8(float* acc, uint4 hv, float wgt) {
    acc[0] += wgt * lo16(hv.x); acc[1] += wgt * hi16(hv.x);
    acc[2] += wgt * lo16(hv.y); acc[3] += wgt * hi16(hv.y);
    acc[4] += wgt * lo16(hv.z); acc[5] += wgt * hi16(hv.z);
    acc[6] += wgt * lo16(hv.w); acc[7] += wgt * hi16(hv.w);
}

#define GLDS16(g, l) __builtin_amdgcn_global_load_lds( \
    (__attribute__((address_space(1))) void*)(g),      \
    (__attribute__((address_space(3))) void*)(l), 16, 0, 0)

// ---------------- prep: x->bf16, zero pads, zero cnt (one kernel) ----------------
#define CVTX_BLK 10000
__global__ __launch_bounds__(256) void k_prep(const float4* __restrict__ xin,
                                              uint4* __restrict__ xb,
                                              uint4* __restrict__ curb,
                                              uint4* __restrict__ cnt4) {
    int bid = blockIdx.x;
    int tid = threadIdx.x;
    if (bid < CVTX_BLK) {
        size_t i = (size_t)bid * 256 + tid;
        float4 a = xin[i * 2], b = xin[i * 2 + 1];
        uint4 o;
        o.x = (unsigned)f2b(a.x) | ((unsigned)f2b(a.y) << 16);
        o.y = (unsigned)f2b(a.z) | ((unsigned)f2b(a.w) << 16);
        o.z = (unsigned)f2b(b.x) | ((unsigned)f2b(b.y) << 16);
        o.w = (unsigned)f2b(b.z) | ((unsigned)f2b(b.w) << 16);
        xb[i] = o;
    } else if (bid < CVTX_BLK + 16) {
        int i = (bid - CVTX_BLK) * 256 + tid;     // < 4096
        xb[(size_t)N_NODES * DINC / 8 + i] = make_uint4(0, 0, 0, 0);
    } else if (bid < CVTX_BLK + 32) {
        int i = (bid - CVTX_BLK - 16) * 256 + tid;
        curb[(size_t)N_NODES * DINC / 8 + i] = make_uint4(0, 0, 0, 0);
    } else {
        int i = (bid - CVTX_BLK - 32) * 256 + tid;
        if (i < N_NODES / 4) cnt4[i] = make_uint4(0, 0, 0, 0);
    }
}

// ---------------- all weight conversions (one kernel) ----------------
// W [K][Nn] f32 -> Wt [Nn][K] bf16, 5 jobs concatenated
__global__ __launch_bounds__(256) void k_cvtw_all(const float* __restrict__ W1, unsigned short* __restrict__ T1,
                                                  const float* __restrict__ W2, unsigned short* __restrict__ T2,
                                                  const float* __restrict__ W3, unsigned short* __restrict__ T3,
                                                  const float* __restrict__ Wg1, const float* __restrict__ Wf1,
                                                  unsigned short* __restrict__ Wct) {
    int idx = blockIdx.x * 256 + threadIdx.x;
    const float* W; unsigned short* T; int Nn;
    if (idx < 262144)            { W = W1; T = T1; Nn = 512; }
    else if (idx < 524288)       { W = W2; T = T2; Nn = 512; idx -= 262144; }
    else if (idx < 786432)       { W = W3; T = T3; Nn = 512; idx -= 524288; }
    else if (idx < 851968)       { W = Wg1; T = Wct; Nn = 128; idx -= 786432; }
    else                         { W = Wf1; T = Wct + 65536; Nn = 128; idx -= 851968; }
    int k = idx / Nn, n = idx % Nn;
    T[(size_t)n * 512 + k] = f2b(W[idx]);
}

// ---------------- CSR build ----------------
__global__ void k_degree(const int* __restrict__ ei, int* __restrict__ cnt) {
    int e = blockIdx.x * 256 + threadIdx.x;
    if (e < ETOT) {
        int dst = (e < N_EDGES) ? ei[N_EDGES + e] : (e - N_EDGES);
        atomicAdd(&cnt[dst], 1);
    }
}

__global__ __launch_bounds__(64) void k_scan1(const int* __restrict__ deg, int* __restrict__ bsum) {
    int lane = threadIdx.x;
    int v = deg[blockIdx.x * 64 + lane];
#pragma unroll
    for (int off = 32; off; off >>= 1) v += __shfl_xor(v, off);
    if (lane == 0) bsum[blockIdx.x] = v;
}

// fused scan2+scan3: block b computes its global prefix from bsum, then local
// wave scan of its 64 degrees; also re-zeroes cnt for k_fill.
__global__ __launch_bounds__(64) void k_scan23(const int* __restrict__ deg, const int* __restrict__ bsum,
                                               int* __restrict__ rowptr, int* __restrict__ cnt) {
    int b = blockIdx.x, lane = threadIdx.x;
    int pre = 0;
    for (int i = lane; i < b; i += 64) pre += bsum[i];
#pragma unroll
    for (int off = 32; off; off >>= 1) pre += __shfl_xor(pre, off);
    int i = b * 64 + lane;
    int v = deg[i];
    int inc = v;
#pragma unroll
    for (int off = 1; off < 64; off <<= 1) {
        int t = __shfl_up(inc, off);
        if (lane >= off) inc += t;
    }
    rowptr[i] = pre + inc - v;
    cnt[i] = 0;
    if (b == 624 && lane == 63) rowptr[N_NODES] = ETOT;
}

__global__ void k_fill(const int* __restrict__ ei, const int* __restrict__ rowptr,
                       int* __restrict__ cnt, int* __restrict__ csr_src) {
    int e = blockIdx.x * 256 + threadIdx.x;
    if (e < ETOT) {
        int src, dst;
        if (e < N_EDGES) { src = ei[e]; dst = ei[N_EDGES + e]; }
        else             { src = e - N_EDGES; dst = src; }
        int pos = rowptr[dst] + atomicAdd(&cnt[dst], 1);
        csr_src[pos] = src;
    }
}

// ---------------- bf16 MFMA GEMM + fused epilogues ----------------
// EPI=1: per-layer es/ed epilogue. EPI=2: scores(G half)/relu-F(F half).
template<int CBF16, int EPI>
__global__ __launch_bounds__(256) void k_gemm_mfma(const unsigned short* __restrict__ A,
                                                   const unsigned short* __restrict__ Bt,
                                                   void* __restrict__ Cout,
                                                   int Nn, int K, int nbn,
                                                   const float* __restrict__ p1,   // as_ | bg1
                                                   const float* __restrict__ p2,   // ad_ | Wg2
                                                   float* __restrict__ p3,         // es  | scores
                                                   float* __restrict__ p4,         // ed  | Fb
                                                   const float* __restrict__ p5,   // -   | bg2
                                                   const float* __restrict__ p6) { // -   | bf1
    __shared__ alignas(16) unsigned short As[128 * 64];
    __shared__ alignas(16) unsigned short Bs[128 * 64];
    const int tid  = threadIdx.x;
    const int wv   = tid >> 6;
    const int lane = tid & 63;
    const int bm = (blockIdx.x / nbn) * 128;
    const int bn = (blockIdx.x % nbn) * 128;
    const int wm = (wv >> 1) * 64;
    const int wn = (wv & 1) * 64;

    const int srow = lane >> 3;
    const int scol = (((lane & 7) ^ srow) * 8);
    const size_t a_base = (size_t)(bm + wv * 32 + srow) * K + scol;
    const size_t b_base = (size_t)(bn + wv * 32 + srow) * K + scol;

    f32x4 acc[4][4] = {};

    for (int k0 = 0; k0 < K; k0 += 64) {
#pragma unroll
        for (int q = 0; q < 4; ++q)
            GLDS16(A + a_base + (size_t)q * 8 * K + k0, &As[(wv * 32 + q * 8) * 64]);
#pragma unroll
        for (int q = 0; q < 4; ++q)
            GLDS16(Bt + b_base + (size_t)q * 8 * K + k0, &Bs[(wv * 32 + q * 8) * 64]);
        __syncthreads();

        const int r0 = lane & 15;
#pragma unroll
        for (int ks = 0; ks < 2; ++ks) {
            const int c = ks * 4 + (lane >> 4);
            bf16x8 af[4], bfr[4];
#pragma unroll
            for (int i = 0; i < 4; ++i) {
                int row = wm + i * 16 + r0;
                af[i] = *(const bf16x8*)&As[row * 64 + ((c ^ (row & 7)) * 8)];
            }
#pragma unroll
            for (int j = 0; j < 4; ++j) {
                int row = wn + j * 16 + r0;
                bfr[j] = *(const bf16x8*)&Bs[row * 64 + ((c ^ (row & 7)) * 8)];
            }
#pragma unroll
            for (int i = 0; i < 4; ++i)
#pragma unroll
                for (int j = 0; j < 4; ++j)
                    acc[i][j] = __builtin_amdgcn_mfma_f32_16x16x32_bf16(af[i], bfr[j], acc[i][j], 0, 0, 0);
        }
        __syncthreads();
    }

    const int crow0 = bm + wm + (lane >> 4) * 4;
    const int ccol  = bn + wn + (lane & 15);

    if (EPI != 2) {
#pragma unroll
        for (int i = 0; i < 4; ++i)
#pragma unroll
            for (int j = 0; j < 4; ++j)
#pragma unroll
                for (int r = 0; r < 4; ++r) {
                    size_t off = (size_t)(crow0 + i * 16 + r) * Nn + ccol + j * 16;
                    if (CBF16) ((unsigned short*)Cout)[off] = f2b(acc[i][j][r]);
                    else       ((float*)Cout)[off] = acc[i][j][r];
                }
    }

    if (EPI == 1) {
        // block covers cols [bn, bn+128) == head bn>>7 entirely -> full es/ed rows
        const int head = bn >> 7;
        float asv[4], adv[4];
#pragma unroll
        for (int j = 0; j < 4; ++j) {
            int cc = head * CHD + wn + j * 16 + (lane & 15);
            asv[j] = p1[cc];
            adv[j] = p2[cc];
        }
        float* sE = (float*)As;          // reuse LDS: 128 es + 128 ed
        sE[tid] = 0.f;
        __syncthreads();
#pragma unroll
        for (int i = 0; i < 4; ++i)
#pragma unroll
            for (int r = 0; r < 4; ++r) {
                float e = acc[i][0][r] * asv[0] + acc[i][1][r] * asv[1]
                        + acc[i][2][r] * asv[2] + acc[i][3][r] * asv[3];
                float d = acc[i][0][r] * adv[0] + acc[i][1][r] * adv[1]
                        + acc[i][2][r] * adv[2] + acc[i][3][r] * adv[3];
#pragma unroll
                for (int off = 8; off; off >>= 1) {
                    e += __shfl_xor(e, off);
                    d += __shfl_xor(d, off);
                }
                if ((lane & 15) == 0) {
                    int rloc = wm + i * 16 + (lane >> 4) * 4 + r;
                    atomicAdd(&sE[rloc], e);
                    atomicAdd(&sE[128 + rloc], d);
                }
            }
        __syncthreads();
        if (tid < 128) {
            p3[(size_t)(bm + tid) * NHEAD + head] = sE[tid];
            p4[(size_t)(bm + tid) * NHEAD + head] = sE[128 + tid];
        }
    }

    if (EPI == 2) {
        if (bn == 0) {
            // G half: score[row] = sum_col tanh(g+bg1)*Wg2 + bg2
            float wgv[4], bgv[4];
#pragma unroll
            for (int j = 0; j < 4; ++j) {
                int cc = wn + j * 16 + (lane & 15);
                bgv[j] = p1[cc];
                wgv[j] = p2[cc];
            }
            float* sE = (float*)As;
            sE[tid] = 0.f;
            __syncthreads();
#pragma unroll
            for (int i = 0; i < 4; ++i)
#pragma unroll
                for (int r = 0; r < 4; ++r) {
                    float e = tanhf(acc[i][0][r] + bgv[0]) * wgv[0]
                            + tanhf(acc[i][1][r] + bgv[1]) * wgv[1]
                            + tanhf(acc[i][2][r] + bgv[2]) * wgv[2]
                            + tanhf(acc[i][3][r] + bgv[3]) * wgv[3];
#pragma unroll
                    for (int off = 8; off; off >>= 1) e += __shfl_xor(e, off);
                    if ((lane & 15) == 0)
                        atomicAdd(&sE[wm + i * 16 + (lane >> 4) * 4 + r], e);
                }
            __syncthreads();
            if (tid < 128) p3[bm + tid] = sE[tid] + p5[0];
        } else {
            // F half: Fb[row][col] = relu(f + bf1[col])
#pragma unroll
            for (int j = 0; j < 4; ++j) {
                int colF = wn + j * 16 + (lane & 15);
                float bv = p6[colF];
#pragma unroll
                for (int i = 0; i < 4; ++i)
#pragma unroll
                    for (int r = 0; r < 4; ++r)
                        p4[(size_t)(crow0 + i * 16 + r) * 128 + colF] =
                            fmaxf(acc[i][j][r] + bv, 0.f);
            }
        }
    }
}

// ---------------- per-edge softmax weights: one wave per node (r7 proven) ----
// wbuf now packed bf16: uint2 per edge = {h0|h1<<16, h2|h3<<16}
__global__ __launch_bounds__(256) void k_wts(const float4* __restrict__ es4,
                                             const float4* __restrict__ ed4,
                                             const int* __restrict__ rowptr,
                                             const int* __restrict__ csr_src,
                                             uint2* __restrict__ wbuf2,
                                             float4* __restrict__ inv4,
                                             float* __restrict__ stats) {
    if (blockIdx.x == 0)
        for (int q = threadIdx.x; q < DINC * 2; q += 256) stats[q] = 0.f;
    int n = blockIdx.x * 4 + (threadIdx.x >> 6);
    int lane = threadIdx.x & 63;
    int start = rowptr[n], end = rowptr[n + 1];
    float4 edn = ed4[n];
    float4 mx = make_float4(-1e30f, -1e30f, -1e30f, -1e30f);
    for (int j0 = start; j0 < end; j0 += 64) {
        int j = j0 + lane;
        if (j < end) {
            int s = csr_src[j];
            float4 e = es4[s];
            mx.x = fmaxf(mx.x, lrelu(e.x + edn.x));
            mx.y = fmaxf(mx.y, lrelu(e.y + edn.y));
            mx.z = fmaxf(mx.z, lrelu(e.z + edn.z));
            mx.w = fmaxf(mx.w, lrelu(e.w + edn.w));
        }
    }
#pragma unroll
    for (int off = 32; off; off >>= 1) {
        mx.x = fmaxf(mx.x, __shfl_xor(mx.x, off));
        mx.y = fmaxf(mx.y, __shfl_xor(mx.y, off));
        mx.z = fmaxf(mx.z, __shfl_xor(mx.z, off));
        mx.w = fmaxf(mx.w, __shfl_xor(mx.w, off));
    }
    float4 sum = make_float4(0.f, 0.f, 0.f, 0.f);
    for (int j0 = start; j0 < end; j0 += 64) {
        int j = j0 + lane;
        if (j < end) {
            int s = csr_src[j];
            float4 e = es4[s];
            float4 ex;
            ex.x = __expf(lrelu(e.x + edn.x) - mx.x);
            ex.y = __expf(lrelu(e.y + edn.y) - mx.y);
            ex.z = __expf(lrelu(e.z + edn.z) - mx.z);
            ex.w = __expf(lrelu(e.w + edn.w) - mx.w);
            wbuf2[j] = make_uint2((unsigned)f2b(ex.x) | ((unsigned)f2b(ex.y) << 16),
                                  (unsigned)f2b(ex.z) | ((unsigned)f2b(ex.w) << 16));
            sum.x += ex.x; sum.y += ex.y; sum.z += ex.z; sum.w += ex.w;
        }
    }
#pragma unroll
    for (int off = 32; off; off >>= 1) {
        sum.x += __shfl_xor(sum.x, off);
        sum.y += __shfl_xor(sum.y, off);
        sum.z += __shfl_xor(sum.z, off);
        sum.w += __shfl_xor(sum.w, off);
    }
    if (lane == 0) {
        float4 iv;
        iv.x = 1.f / (sum.x + 1e-16f);
        iv.y = 1.f / (sum.y + 1e-16f);
        iv.z = 1.f / (sum.z + 1e-16f);
        iv.w = 1.f / (sum.w + 1e-16f);
        inv4[n] = iv;
    }
}

// ---------------- aggregate: block/node, 4 groups x 64 lanes, 2-deep prefetch ----------------
// (r3/r7 proven structure: 96.5us; wave-per-node, inline-weight, and
// LDS-prologue fused variants all regressed — avg degree 17 is too small)
__global__ __launch_bounds__(256) void k_agg(const unsigned short* __restrict__ hb,
                                             const int* __restrict__ rowptr,
                                             const int* __restrict__ csr_src,
                                             const unsigned* __restrict__ wbufu,
                                             const float* __restrict__ invp,
                                             unsigned short* __restrict__ aggb) {
    __shared__ float part[4][512];
    const int n = blockIdx.x;
    const int tid = threadIdx.x;
    const int grp = tid >> 6;
    const int lane = tid & 63;
    const int head = lane >> 4;
    const int hh = head >> 1;          // which packed word
    const int start = rowptr[n], end = rowptr[n + 1];

    float acc[8] = {};
    int j = start + grp;
    int s_n = 0; unsigned wu_n = 0;
    if (j < end) { s_n = csr_src[j]; wu_n = wbufu[j * 2 + hh]; }
    while (j < end) {
        int s = s_n; unsigned wu = wu_n;
        int j2 = j + 4;
        if (j2 < end) { s_n = csr_src[j2]; wu_n = wbufu[j2 * 2 + hh]; }
        float wgt = (head & 1) ? hi16(wu) : lo16(wu);
        uint4 hv = *(const uint4*)&hb[(size_t)s * DINC + lane * 8];
        fma8(acc, hv, wgt);
        j = j2;
    }
    *(float4*)&part[grp][lane * 8]     = make_float4(acc[0], acc[1], acc[2], acc[3]);
    *(float4*)&part[grp][lane * 8 + 4] = make_float4(acc[4], acc[5], acc[6], acc[7]);
    __syncthreads();
    const int c = tid * 2;
    float v0 = part[0][c] + part[1][c] + part[2][c] + part[3][c];
    float v1 = part[0][c + 1] + part[1][c + 1] + part[2][c + 1] + part[3][c + 1];
    float iv = invp[(n << 2) + (c >> 7)];
    v0 *= iv; v1 *= iv;
    unsigned int o = (unsigned)f2b(v0) | ((unsigned)f2b(v1) << 16);
    *(unsigned int*)&aggb[(size_t)n * DINC + c] = o;
}

// ---------------- BatchNorm (bf16 agg) ----------------
__global__ __launch_bounds__(256) void k_bn_stats(const unsigned short* __restrict__ aggb,
                                                  float* __restrict__ stats) {
    int tid = threadIdx.x;
    int row0 = blockIdx.x * 64;
    int c0 = tid * 2;
    float s0 = 0, q0 = 0, s1 = 0, q1 = 0;
    for (int r = row0; r < row0 + 64; ++r) {
        unsigned int hv = *(const unsigned int*)&aggb[(size_t)r * DINC + c0];
        float v0 = lo16(hv), v1 = hi16(hv);
        s0 += v0; q0 += v0 * v0;
        s1 += v1; q1 += v1 * v1;
    }
    atomicAdd(&stats[c0], s0);
    atomicAdd(&stats[c0 + 1], s1);
    atomicAdd(&stats[DINC + c0], q0);
    atomicAdd(&stats[DINC + c0 + 1], q1);
}

// bn_act with fused bn_fin: each thread derives A,B for its 8 channels from stats
__global__ __launch_bounds__(256) void k_bn_act(const unsigned short* __restrict__ aggb,
                                                const float* __restrict__ stats,
                                                const float* __restrict__ g,
                                                const float* __restrict__ be,
                                                unsigned short* __restrict__ curb,
                                                int res) {
    size_t idx = (size_t)blockIdx.x * 256 + threadIdx.x;   // < N*64, 8 ch each
    int c8 = ((int)(idx & 63)) * 8;
    uint4 v = *(const uint4*)&aggb[idx * 8];
    float xv[8] = { lo16(v.x), hi16(v.x), lo16(v.y), hi16(v.y),
                    lo16(v.z), hi16(v.z), lo16(v.w), hi16(v.w) };
#pragma unroll
    for (int q = 0; q < 8; ++q) {
        int c = c8 + q;
        float mu = stats[c] * (1.f / N_NODES);
        float var = stats[DINC + c] * (1.f / N_NODES) - mu * mu;
        float A = g[c] * rsqrtf(var + BN_EPS);
        float B = be[c] - mu * A;
        xv[q] = lrelu(xv[q] * A + B);
    }
    if (res) {
        uint4 r = *(const uint4*)&curb[idx * 8];
        xv[0] += lo16(r.x); xv[1] += hi16(r.x);
        xv[2] += lo16(r.y); xv[3] += hi16(r.y);
        xv[4] += lo16(r.z); xv[5] += hi16(r.z);
        xv[6] += lo16(r.w); xv[7] += hi16(r.w);
    }
    uint4 o;
    o.x = (unsigned)f2b(xv[0]) | ((unsigned)f2b(xv[1]) << 16);
    o.y = (unsigned)f2b(xv[2]) | ((unsigned)f2b(xv[3]) << 16);
    o.z = (unsigned)f2b(xv[4]) | ((unsigned)f2b(xv[5]) << 16);
    o.w = (unsigned)f2b(xv[6]) | ((unsigned)f2b(xv[7]) << 16);
    *(uint4*)&curb[idx * 8] = o;
}

// ---------------- epilogue ----------------
__global__ __launch_bounds__(1024) void k_softmax(const float4* __restrict__ scores4,
                                                  const float* __restrict__ scores,
                                                  float* __restrict__ sm,
                                                  float* __restrict__ vbuf, float* __restrict__ pooled) {
    __shared__ float red[16];
    int tid = threadIdx.x, lane = tid & 63, wv = tid >> 6;
    if (tid < 128) vbuf[tid] = 0.f;
    if (tid < DINC) pooled[tid] = 0.f;
    float m = -1e30f;
    for (int i = tid; i < N_NODES / 4; i += 1024) {
        float4 s4 = scores4[i];
        m = fmaxf(fmaxf(fmaxf(m, s4.x), fmaxf(s4.y, s4.z)), s4.w);
    }
#pragma unroll
    for (int off = 32; off; off >>= 1) m = fmaxf(m, __shfl_xor(m, off));
    if (lane == 0) red[wv] = m;
    __syncthreads();
    float mall = red[0];
    for (int i = 1; i < 16; ++i) mall = fmaxf(mall, red[i]);
    __syncthreads();
    float s = 0.f;
    for (int i = tid; i < N_NODES / 4; i += 1024) {
        float4 s4 = scores4[i];
        s += __expf(s4.x - mall) + __expf(s4.y - mall) + __expf(s4.z - mall) + __expf(s4.w - mall);
    }
#pragma unroll
    for (int off = 32; off; off >>= 1) s += __shfl_xor(s, off);
    if (lane == 0) red[wv] = s;
    __syncthreads();
    if (tid == 0) {
        float tot = 0.f;
        for (int i = 0; i < 16; ++i) tot += red[i];
        sm[0] = mall; sm[1] = tot;
    }
}

__global__ __launch_bounds__(384) void k_vpool(const float* __restrict__ Fb,
                                               const unsigned short* __restrict__ hb,
                                               const float* __restrict__ scores,
                                               const float* __restrict__ sm,
                                               float* __restrict__ v,
                                               float* __restrict__ pooled) {
    int tid = threadIdx.x;
    int row0 = blockIdx.x * 64;
    float mall = sm[0];
    float invS = 1.f / sm[1];
    if (tid < 128) {
        float acc = 0.f;
        for (int r = row0; r < row0 + 64; ++r) {
            float w = __expf(scores[r] - mall) * invS;
            acc += w * Fb[(size_t)r * 128 + tid];
        }
        atomicAdd(&v[tid], acc);
    } else {
        int c = (tid - 128) * 2;
        float a0 = 0.f, a1 = 0.f;
        for (int r = row0; r < row0 + 64; ++r) {
            unsigned int hv = *(const unsigned int*)&hb[(size_t)r * DINC + c];
            a0 += lo16(hv); a1 += hi16(hv);
        }
        atomicAdd(&pooled[c], a0 * (1.f / N_NODES));
        atomicAdd(&pooled[c + 1], a1 * (1.f / N_NODES));
    }
}

__global__ __launch_bounds__(128) void k_final(const float* __restrict__ v,
                                               const float* __restrict__ pooled,
                                               const float* __restrict__ Wf2,
                                               const float* __restrict__ bf2,
                                               const float* __restrict__ Wp,
                                               const float* __restrict__ bp,
                                               float* __restrict__ out) {
    __shared__ float sg[128];
    int o = threadIdx.x;
    float g = bf2[o];
    for (int k = 0; k < 128; ++k) g += v[k] * Wf2[k * 128 + o];
    sg[o] = g;
    __syncthreads();
    float acc = bp[o];
    for (int c = 0; c < 128; ++c) acc += sg[c] * Wp[c * 128 + o];
    for (int j = 0; j < 512; ++j) acc += pooled[j] * Wp[(128 + j) * 128 + o];
    out[o] = acc;
}

// ---------------- host launch ----------------
extern "C" void kernel_launch(void* const* d_in, const int* in_sizes, int n_in,
                              void* d_out, int out_size, void* d_ws, size_t ws_size,
                              hipStream_t stream) {
    const float* x  = (const float*)d_in[0];
    const int*   ei = (const int*)d_in[1];
    const float* Wg1 = (const float*)d_in[20];
    const float* bg1 = (const float*)d_in[21];
    const float* Wg2 = (const float*)d_in[22];
    const float* bg2 = (const float*)d_in[23];
    const float* Wf1 = (const float*)d_in[24];
    const float* bf1 = (const float*)d_in[25];
    const float* Wf2 = (const float*)d_in[26];
    const float* bf2 = (const float*)d_in[27];
    const float* Wp  = (const float*)d_in[28];
    const float* bp  = (const float*)d_in[29];
    float* out = (float*)d_out;

    char* base = (char*)d_ws;
    size_t off = 0;
    auto take = [&](size_t nbytes) -> char* {
        char* p = base + off;
        off += (nbytes + 255) & ~(size_t)255;
        return p;
    };
    unsigned short* hb   = (unsigned short*)take((size_t)M_PAD * DINC * 2);
    unsigned short* curb = (unsigned short*)take((size_t)M_PAD * DINC * 2);
    unsigned short* xb   = (unsigned short*)take((size_t)M_PAD * DINC * 2);
    unsigned short* aggb = (unsigned short*)take((size_t)M_PAD * DINC * 2);
    float* Fb    = (float*)take((size_t)M_PAD * 128 * 4);
    float* es    = (float*)take((size_t)M_PAD * NHEAD * 4);
    float* ed    = (float*)take((size_t)M_PAD * NHEAD * 4);
    uint2* wbuf  = (uint2*)take((size_t)ETOT * 8);
    float* invp  = (float*)take((size_t)N_NODES * NHEAD * 4);
    int*   rowptr= (int*)take((size_t)(N_NODES + 1) * 4);
    int*   cnt   = (int*)take((size_t)N_NODES * 4);
    int*   csr   = (int*)take((size_t)ETOT * 4);
    int*   bsum  = (int*)take(625 * 4);
    float* stats = (float*)take(DINC * 2 * 4);
    float* sm    = (float*)take(2 * 4);
    float* vbuf  = (float*)take(128 * 4);
    float* pooled= (float*)take(DINC * 4);
    unsigned short* Wt1  = (unsigned short*)take((size_t)DINC * DINC * 2);
    unsigned short* Wt2  = (unsigned short*)take((size_t)DINC * DINC * 2);
    unsigned short* Wt3  = (unsigned short*)take((size_t)DINC * DINC * 2);
    unsigned short* Wct  = (unsigned short*)take((size_t)256 * DINC * 2);

    // prep + conversions + CSR build
    k_prep<<<CVTX_BLK + 32 + 40, 256, 0, stream>>>((const float4*)x, (uint4*)xb,
                                                   (uint4*)curb, (uint4*)cnt);
    k_cvtw_all<<<3584, 256, 0, stream>>>((const float*)d_in[2], Wt1,
                                         (const float*)d_in[8], Wt2,
                                         (const float*)d_in[14], Wt3,
                                         Wg1, Wf1, Wct);
    k_degree<<<(ETOT + 255) / 256, 256, 0, stream>>>(ei, cnt);
    k_scan1<<<625, 64, 0, stream>>>(cnt, bsum);
    k_scan23<<<625, 64, 0, stream>>>(cnt, bsum, rowptr, cnt);
    k_fill<<<(ETOT + 255) / 256, 256, 0, stream>>>(ei, rowptr, cnt, csr);

    const unsigned short* Wts[3] = {Wt1, Wt2, Wt3};
    const unsigned short* in = xb;
    for (int l = 0; l < 3; ++l) {
        const float* as_ = (const float*)d_in[2 + l * 6 + 1];
        const float* ad_ = (const float*)d_in[2 + l * 6 + 2];
        const float* g   = (const float*)d_in[2 + l * 6 + 4];
        const float* be  = (const float*)d_in[2 + l * 6 + 5];

        k_gemm_mfma<1, 1><<<(M_PAD / 128) * (DINC / 128), 256, 0, stream>>>(
            in, Wts[l], hb, DINC, DINC, DINC / 128, as_, ad_, es, ed, nullptr, nullptr);
        k_wts<<<N_NODES / 4, 256, 0, stream>>>((const float4*)es, (const float4*)ed, rowptr, csr,
                                               wbuf, (float4*)invp, stats);
        k_agg<<<N_NODES, 256, 0, stream>>>(hb, rowptr, csr, (const unsigned*)wbuf, invp, aggb);
        k_bn_stats<<<N_NODES / 64, 256, 0, stream>>>(aggb, stats);
        k_bn_act<<<(N_NODES * (DINC / 8)) / 256, 256, 0, stream>>>(aggb, stats, g, be, curb, l > 0 ? 1 : 0);
        in = curb;
    }

    // fused epilogue GEMM: [M,512] @ [512,256]; G half -> scores, F half -> relu F
    float* scores = out + 128;
    k_gemm_mfma<0, 2><<<(M_PAD / 128) * 2, 256, 0, stream>>>(
        curb, Wct, nullptr, 256, DINC, 2, bg1, Wg2, scores, Fb, bg2, bf1);

    k_softmax<<<1, 1024, 0, stream>>>((const float4*)scores, scores, sm, vbuf, pooled);
    k_vpool<<<N_NODES / 64, 384, 0, stream>>>(Fb, curb, scores, sm, vbuf, pooled);
    k_final<<<1, 128, 0, stream>>>(vbuf, pooled, Wf2, bf2, Wp, bp, out);
}

// Round 10
// 836.219 us; speedup vs baseline: 1.0991x; 1.0522x over previous
//
#include <hip/hip_runtime.h>
#include <math.h>

#define N_NODES 40000
#define M_PAD   40064          // 313 * 128
#define N_EDGES 640000
#define ETOT    (N_EDGES + N_NODES)
#define DINC    512            // DIN == H*C
#define NHEAD   4
#define CHD     128
#define BN_EPS  1e-5f

typedef __attribute__((ext_vector_type(8))) short bf16x8;
typedef __attribute__((ext_vector_type(4))) float f32x4;

static __device__ __forceinline__ float lrelu(float x) { return x > 0.f ? x : 0.2f * x; }

static __device__ __forceinline__ unsigned short f2b(float f) {
    union { float f; unsigned int u; } v; v.f = f;
    unsigned int r = (v.u + 0x7fff + ((v.u >> 16) & 1)) >> 16;
    return (unsigned short)r;
}
static __device__ __forceinline__ float b2f(unsigned short b) {
    union { unsigned int u; float f; } v; v.u = ((unsigned int)b) << 16;
    return v.f;
}
static __device__ __forceinline__ float lo16(unsigned int u) {
    union { unsigned int u; float f; } v; v.u = u << 16; return v.f;
}
static __device__ __forceinline__ float hi16(unsigned int u) {
    union { unsigned int u; float f; } v; v.u = u & 0xffff0000u; return v.f;
}

// 8-channel bf16 FMA into f32 accumulators (inline fn, not macro)
static __device__ __forceinline__ void fma8(float* acc, uint4 hv, float wgt) {
    acc[0] += wgt * lo16(hv.x); acc[1] += wgt * hi16(hv.x);
    acc[2] += wgt * lo16(hv.y); acc[3] += wgt * hi16(hv.y);
    acc[4] += wgt * lo16(hv.z); acc[5] += wgt * hi16(hv.z);
    acc[6] += wgt * lo16(hv.w); acc[7] += wgt * hi16(hv.w);
}

#define GLDS16(g, l) __builtin_amdgcn_global_load_lds( \
    (__attribute__((address_space(1))) void*)(g),      \
    (__attribute__((address_space(3))) void*)(l), 16, 0, 0)

// ---------------- prep: x->bf16, zero pads, zero cnt, weight transposes ------
// one kernel: blocks [0,10000) cvtx; +16 xb pad; +16 curb pad; +40 cnt zero;
// +3584 weight-transpose jobs (W[K][Nn] f32 -> Wt[Nn][K] bf16, 5 concatenated)
#define CVTX_BLK 10000
#define PREP_CVTW0 (CVTX_BLK + 72)
__global__ __launch_bounds__(256) void k_prep(const float4* __restrict__ xin,
                                              uint4* __restrict__ xb,
                                              uint4* __restrict__ curb,
                                              uint4* __restrict__ cnt4,
                                              const float* __restrict__ W1, unsigned short* __restrict__ T1,
                                              const float* __restrict__ W2, unsigned short* __restrict__ T2,
                                              const float* __restrict__ W3, unsigned short* __restrict__ T3,
                                              const float* __restrict__ Wg1, const float* __restrict__ Wf1,
                                              unsigned short* __restrict__ Wct) {
    int bid = blockIdx.x;
    int tid = threadIdx.x;
    if (bid < CVTX_BLK) {
        size_t i = (size_t)bid * 256 + tid;
        float4 a = xin[i * 2], b = xin[i * 2 + 1];
        uint4 o;
        o.x = (unsigned)f2b(a.x) | ((unsigned)f2b(a.y) << 16);
        o.y = (unsigned)f2b(a.z) | ((unsigned)f2b(a.w) << 16);
        o.z = (unsigned)f2b(b.x) | ((unsigned)f2b(b.y) << 16);
        o.w = (unsigned)f2b(b.z) | ((unsigned)f2b(b.w) << 16);
        xb[i] = o;
    } else if (bid < CVTX_BLK + 16) {
        int i = (bid - CVTX_BLK) * 256 + tid;     // < 4096
        xb[(size_t)N_NODES * DINC / 8 + i] = make_uint4(0, 0, 0, 0);
    } else if (bid < CVTX_BLK + 32) {
        int i = (bid - CVTX_BLK - 16) * 256 + tid;
        curb[(size_t)N_NODES * DINC / 8 + i] = make_uint4(0, 0, 0, 0);
    } else if (bid < PREP_CVTW0) {
        int i = (bid - CVTX_BLK - 32) * 256 + tid;
        if (i < N_NODES / 4) cnt4[i] = make_uint4(0, 0, 0, 0);
    } else {
        int idx = (bid - PREP_CVTW0) * 256 + tid;
        const float* W; unsigned short* T; int Nn;
        if (idx < 262144)            { W = W1; T = T1; Nn = 512; }
        else if (idx < 524288)       { W = W2; T = T2; Nn = 512; idx -= 262144; }
        else if (idx < 786432)       { W = W3; T = T3; Nn = 512; idx -= 524288; }
        else if (idx < 851968)       { W = Wg1; T = Wct; Nn = 128; idx -= 786432; }
        else                         { W = Wf1; T = Wct + 65536; Nn = 128; idx -= 851968; }
        int k = idx / Nn, n = idx % Nn;
        T[(size_t)n * 512 + k] = f2b(W[idx]);
    }
}

// ---------------- CSR build ----------------
__global__ void k_degree(const int* __restrict__ ei, int* __restrict__ cnt) {
    int e = blockIdx.x * 256 + threadIdx.x;
    if (e < ETOT) {
        int dst = (e < N_EDGES) ? ei[N_EDGES + e] : (e - N_EDGES);
        atomicAdd(&cnt[dst], 1);
    }
}

__global__ __launch_bounds__(64) void k_scan1(const int* __restrict__ deg, int* __restrict__ bsum) {
    int lane = threadIdx.x;
    int v = deg[blockIdx.x * 64 + lane];
#pragma unroll
    for (int off = 32; off; off >>= 1) v += __shfl_xor(v, off);
    if (lane == 0) bsum[blockIdx.x] = v;
}

// fused scan2+scan3: block b computes its global prefix from bsum, then local
// wave scan of its 64 degrees; also re-zeroes cnt for k_fill.
__global__ __launch_bounds__(64) void k_scan23(const int* __restrict__ deg, const int* __restrict__ bsum,
                                               int* __restrict__ rowptr, int* __restrict__ cnt) {
    int b = blockIdx.x, lane = threadIdx.x;
    int pre = 0;
    for (int i = lane; i < b; i += 64) pre += bsum[i];
#pragma unroll
    for (int off = 32; off; off >>= 1) pre += __shfl_xor(pre, off);
    int i = b * 64 + lane;
    int v = deg[i];
    int inc = v;
#pragma unroll
    for (int off = 1; off < 64; off <<= 1) {
        int t = __shfl_up(inc, off);
        if (lane >= off) inc += t;
    }
    rowptr[i] = pre + inc - v;
    cnt[i] = 0;
    if (b == 624 && lane == 63) rowptr[N_NODES] = ETOT;
}

__global__ void k_fill(const int* __restrict__ ei, const int* __restrict__ rowptr,
                       int* __restrict__ cnt, int* __restrict__ csr_src) {
    int e = blockIdx.x * 256 + threadIdx.x;
    if (e < ETOT) {
        int src, dst;
        if (e < N_EDGES) { src = ei[e]; dst = ei[N_EDGES + e]; }
        else             { src = e - N_EDGES; dst = src; }
        int pos = rowptr[dst] + atomicAdd(&cnt[dst], 1);
        csr_src[pos] = src;
    }
}

// ---------------- bf16 MFMA GEMM + fused epilogues ----------------
// EPI=1: per-layer es/ed epilogue. EPI=2: scores(G half)/relu-F(F half).
template<int CBF16, int EPI>
__global__ __launch_bounds__(256) void k_gemm_mfma(const unsigned short* __restrict__ A,
                                                   const unsigned short* __restrict__ Bt,
                                                   void* __restrict__ Cout,
                                                   int Nn, int K, int nbn,
                                                   const float* __restrict__ p1,   // as_ | bg1
                                                   const float* __restrict__ p2,   // ad_ | Wg2
                                                   float* __restrict__ p3,         // es  | scores
                                                   float* __restrict__ p4,         // ed  | Fb
                                                   const float* __restrict__ p5,   // -   | bg2
                                                   const float* __restrict__ p6) { // -   | bf1
    __shared__ alignas(16) unsigned short As[128 * 64];
    __shared__ alignas(16) unsigned short Bs[128 * 64];
    const int tid  = threadIdx.x;
    const int wv   = tid >> 6;
    const int lane = tid & 63;
    const int bm = (blockIdx.x / nbn) * 128;
    const int bn = (blockIdx.x % nbn) * 128;
    const int wm = (wv >> 1) * 64;
    const int wn = (wv & 1) * 64;

    const int srow = lane >> 3;
    const int scol = (((lane & 7) ^ srow) * 8);
    const size_t a_base = (size_t)(bm + wv * 32 + srow) * K + scol;
    const size_t b_base = (size_t)(bn + wv * 32 + srow) * K + scol;

    f32x4 acc[4][4] = {};

    for (int k0 = 0; k0 < K; k0 += 64) {
#pragma unroll
        for (int q = 0; q < 4; ++q)
            GLDS16(A + a_base + (size_t)q * 8 * K + k0, &As[(wv * 32 + q * 8) * 64]);
#pragma unroll
        for (int q = 0; q < 4; ++q)
            GLDS16(Bt + b_base + (size_t)q * 8 * K + k0, &Bs[(wv * 32 + q * 8) * 64]);
        __syncthreads();

        const int r0 = lane & 15;
#pragma unroll
        for (int ks = 0; ks < 2; ++ks) {
            const int c = ks * 4 + (lane >> 4);
            bf16x8 af[4], bfr[4];
#pragma unroll
            for (int i = 0; i < 4; ++i) {
                int row = wm + i * 16 + r0;
                af[i] = *(const bf16x8*)&As[row * 64 + ((c ^ (row & 7)) * 8)];
            }
#pragma unroll
            for (int j = 0; j < 4; ++j) {
                int row = wn + j * 16 + r0;
                bfr[j] = *(const bf16x8*)&Bs[row * 64 + ((c ^ (row & 7)) * 8)];
            }
#pragma unroll
            for (int i = 0; i < 4; ++i)
#pragma unroll
                for (int j = 0; j < 4; ++j)
                    acc[i][j] = __builtin_amdgcn_mfma_f32_16x16x32_bf16(af[i], bfr[j], acc[i][j], 0, 0, 0);
        }
        __syncthreads();
    }

    const int crow0 = bm + wm + (lane >> 4) * 4;
    const int ccol  = bn + wn + (lane & 15);

    if (EPI != 2) {
#pragma unroll
        for (int i = 0; i < 4; ++i)
#pragma unroll
            for (int j = 0; j < 4; ++j)
#pragma unroll
                for (int r = 0; r < 4; ++r) {
                    size_t off = (size_t)(crow0 + i * 16 + r) * Nn + ccol + j * 16;
                    if (CBF16) ((unsigned short*)Cout)[off] = f2b(acc[i][j][r]);
                    else       ((float*)Cout)[off] = acc[i][j][r];
                }
    }

    if (EPI == 1) {
        // block covers cols [bn, bn+128) == head bn>>7 entirely -> full es/ed rows
        const int head = bn >> 7;
        float asv[4], adv[4];
#pragma unroll
        for (int j = 0; j < 4; ++j) {
            int cc = head * CHD + wn + j * 16 + (lane & 15);
            asv[j] = p1[cc];
            adv[j] = p2[cc];
        }
        float* sE = (float*)As;          // reuse LDS: 128 es + 128 ed
        sE[tid] = 0.f;
        __syncthreads();
#pragma unroll
        for (int i = 0; i < 4; ++i)
#pragma unroll
            for (int r = 0; r < 4; ++r) {
                float e = acc[i][0][r] * asv[0] + acc[i][1][r] * asv[1]
                        + acc[i][2][r] * asv[2] + acc[i][3][r] * asv[3];
                float d = acc[i][0][r] * adv[0] + acc[i][1][r] * adv[1]
                        + acc[i][2][r] * adv[2] + acc[i][3][r] * adv[3];
#pragma unroll
                for (int off = 8; off; off >>= 1) {
                    e += __shfl_xor(e, off);
                    d += __shfl_xor(d, off);
                }
                if ((lane & 15) == 0) {
                    int rloc = wm + i * 16 + (lane >> 4) * 4 + r;
                    atomicAdd(&sE[rloc], e);
                    atomicAdd(&sE[128 + rloc], d);
                }
            }
        __syncthreads();
        if (tid < 128) {
            p3[(size_t)(bm + tid) * NHEAD + head] = sE[tid];
            p4[(size_t)(bm + tid) * NHEAD + head] = sE[128 + tid];
        }
    }

    if (EPI == 2) {
        if (bn == 0) {
            // G half: score[row] = sum_col tanh(g+bg1)*Wg2 + bg2
            float wgv[4], bgv[4];
#pragma unroll
            for (int j = 0; j < 4; ++j) {
                int cc = wn + j * 16 + (lane & 15);
                bgv[j] = p1[cc];
                wgv[j] = p2[cc];
            }
            float* sE = (float*)As;
            sE[tid] = 0.f;
            __syncthreads();
#pragma unroll
            for (int i = 0; i < 4; ++i)
#pragma unroll
                for (int r = 0; r < 4; ++r) {
                    float e = tanhf(acc[i][0][r] + bgv[0]) * wgv[0]
                            + tanhf(acc[i][1][r] + bgv[1]) * wgv[1]
                            + tanhf(acc[i][2][r] + bgv[2]) * wgv[2]
                            + tanhf(acc[i][3][r] + bgv[3]) * wgv[3];
#pragma unroll
                    for (int off = 8; off; off >>= 1) e += __shfl_xor(e, off);
                    if ((lane & 15) == 0)
                        atomicAdd(&sE[wm + i * 16 + (lane >> 4) * 4 + r], e);
                }
            __syncthreads();
            if (tid < 128) p3[bm + tid] = sE[tid] + p5[0];
        } else {
            // F half: Fb[row][col] = relu(f + bf1[col])
#pragma unroll
            for (int j = 0; j < 4; ++j) {
                int colF = wn + j * 16 + (lane & 15);
                float bv = p6[colF];
#pragma unroll
                for (int i = 0; i < 4; ++i)
#pragma unroll
                    for (int r = 0; r < 4; ++r)
                        p4[(size_t)(crow0 + i * 16 + r) * 128 + colF] =
                            fmaxf(acc[i][j][r] + bv, 0.f);
            }
        }
    }
}

// ---------------- per-edge softmax weights: single pass (no max subtraction) --
// |e| is bounded (~6): exp(lrelu(e)) <= ~400, f32-safe; softmax is shift-
// invariant so skipping the max pass is exact up to fp rounding (validated in
// r8's fused variant: absmax unchanged). Halves the random es-gather traffic.
// wbuf packed bf16: uint2 per edge = {h0|h1<<16, h2|h3<<16}
__global__ __launch_bounds__(256) void k_wts(const float4* __restrict__ es4,
                                             const float4* __restrict__ ed4,
                                             const int* __restrict__ rowptr,
                                             const int* __restrict__ csr_src,
                                             uint2* __restrict__ wbuf2,
                                             float4* __restrict__ inv4,
                                             float* __restrict__ stats) {
    if (blockIdx.x == 0)
        for (int q = threadIdx.x; q < DINC * 2; q += 256) stats[q] = 0.f;
    int n = blockIdx.x * 4 + (threadIdx.x >> 6);
    int lane = threadIdx.x & 63;
    int start = rowptr[n], end = rowptr[n + 1];
    float4 edn = ed4[n];
    float4 sum = make_float4(0.f, 0.f, 0.f, 0.f);
    for (int j0 = start; j0 < end; j0 += 64) {
        int j = j0 + lane;
        if (j < end) {
            int s = csr_src[j];
            float4 e = es4[s];
            float4 ex;
            ex.x = __expf(lrelu(e.x + edn.x));
            ex.y = __expf(lrelu(e.y + edn.y));
            ex.z = __expf(lrelu(e.z + edn.z));
            ex.w = __expf(lrelu(e.w + edn.w));
            wbuf2[j] = make_uint2((unsigned)f2b(ex.x) | ((unsigned)f2b(ex.y) << 16),
                                  (unsigned)f2b(ex.z) | ((unsigned)f2b(ex.w) << 16));
            sum.x += ex.x; sum.y += ex.y; sum.z += ex.z; sum.w += ex.w;
        }
    }
#pragma unroll
    for (int off = 32; off; off >>= 1) {
        sum.x += __shfl_xor(sum.x, off);
        sum.y += __shfl_xor(sum.y, off);
        sum.z += __shfl_xor(sum.z, off);
        sum.w += __shfl_xor(sum.w, off);
    }
    if (lane == 0) {
        float4 iv;
        iv.x = 1.f / (sum.x + 1e-16f);
        iv.y = 1.f / (sum.y + 1e-16f);
        iv.z = 1.f / (sum.z + 1e-16f);
        iv.w = 1.f / (sum.w + 1e-16f);
        inv4[n] = iv;
    }
}

// ---------------- aggregate: block/node, 4 groups x 64 lanes, 2-deep prefetch ----------------
// (r3/r7 proven structure: 96us; wave-per-node, inline-weight, and LDS-prologue
// fused variants all regressed — avg degree 17 is too small. DO NOT TOUCH.)
__global__ __launch_bounds__(256) void k_agg(const unsigned short* __restrict__ hb,
                                             const int* __restrict__ rowptr,
                                             const int* __restrict__ csr_src,
                                             const unsigned* __restrict__ wbufu,
                                             const float* __restrict__ invp,
                                             unsigned short* __restrict__ aggb) {
    __shared__ float part[4][512];
    const int n = blockIdx.x;
    const int tid = threadIdx.x;
    const int grp = tid >> 6;
    const int lane = tid & 63;
    const int head = lane >> 4;
    const int hh = head >> 1;          // which packed word
    const int start = rowptr[n], end = rowptr[n + 1];

    float acc[8] = {};
    int j = start + grp;
    int s_n = 0; unsigned wu_n = 0;
    if (j < end) { s_n = csr_src[j]; wu_n = wbufu[j * 2 + hh]; }
    while (j < end) {
        int s = s_n; unsigned wu = wu_n;
        int j2 = j + 4;
        if (j2 < end) { s_n = csr_src[j2]; wu_n = wbufu[j2 * 2 + hh]; }
        float wgt = (head & 1) ? hi16(wu) : lo16(wu);
        uint4 hv = *(const uint4*)&hb[(size_t)s * DINC + lane * 8];
        fma8(acc, hv, wgt);
        j = j2;
    }
    *(float4*)&part[grp][lane * 8]     = make_float4(acc[0], acc[1], acc[2], acc[3]);
    *(float4*)&part[grp][lane * 8 + 4] = make_float4(acc[4], acc[5], acc[6], acc[7]);
    __syncthreads();
    const int c = tid * 2;
    float v0 = part[0][c] + part[1][c] + part[2][c] + part[3][c];
    float v1 = part[0][c + 1] + part[1][c + 1] + part[2][c + 1] + part[3][c + 1];
    float iv = invp[(n << 2) + (c >> 7)];
    v0 *= iv; v1 *= iv;
    unsigned int o = (unsigned)f2b(v0) | ((unsigned)f2b(v1) << 16);
    *(unsigned int*)&aggb[(size_t)n * DINC + c] = o;
}

// ---------------- BatchNorm (bf16 agg) ----------------
__global__ __launch_bounds__(256) void k_bn_stats(const unsigned short* __restrict__ aggb,
                                                  float* __restrict__ stats) {
    int tid = threadIdx.x;
    int row0 = blockIdx.x * 64;
    int c0 = tid * 2;
    float s0 = 0, q0 = 0, s1 = 0, q1 = 0;
    for (int r = row0; r < row0 + 64; ++r) {
        unsigned int hv = *(const unsigned int*)&aggb[(size_t)r * DINC + c0];
        float v0 = lo16(hv), v1 = hi16(hv);
        s0 += v0; q0 += v0 * v0;
        s1 += v1; q1 += v1 * v1;
    }
    atomicAdd(&stats[c0], s0);
    atomicAdd(&stats[c0 + 1], s1);
    atomicAdd(&stats[DINC + c0], q0);
    atomicAdd(&stats[DINC + c0 + 1], q1);
}

// bn_act with fused bn_fin: each thread derives A,B for its 8 channels from stats
__global__ __launch_bounds__(256) void k_bn_act(const unsigned short* __restrict__ aggb,
                                                const float* __restrict__ stats,
                                                const float* __restrict__ g,
                                                const float* __restrict__ be,
                                                unsigned short* __restrict__ curb,
                                                int res) {
    size_t idx = (size_t)blockIdx.x * 256 + threadIdx.x;   // < N*64, 8 ch each
    int c8 = ((int)(idx & 63)) * 8;
    uint4 v = *(const uint4*)&aggb[idx * 8];
    float xv[8] = { lo16(v.x), hi16(v.x), lo16(v.y), hi16(v.y),
                    lo16(v.z), hi16(v.z), lo16(v.w), hi16(v.w) };
#pragma unroll
    for (int q = 0; q < 8; ++q) {
        int c = c8 + q;
        float mu = stats[c] * (1.f / N_NODES);
        float var = stats[DINC + c] * (1.f / N_NODES) - mu * mu;
        float A = g[c] * rsqrtf(var + BN_EPS);
        float B = be[c] - mu * A;
        xv[q] = lrelu(xv[q] * A + B);
    }
    if (res) {
        uint4 r = *(const uint4*)&curb[idx * 8];
        xv[0] += lo16(r.x); xv[1] += hi16(r.x);
        xv[2] += lo16(r.y); xv[3] += hi16(r.y);
        xv[4] += lo16(r.z); xv[5] += hi16(r.z);
        xv[6] += lo16(r.w); xv[7] += hi16(r.w);
    }
    uint4 o;
    o.x = (unsigned)f2b(xv[0]) | ((unsigned)f2b(xv[1]) << 16);
    o.y = (unsigned)f2b(xv[2]) | ((unsigned)f2b(xv[3]) << 16);
    o.z = (unsigned)f2b(xv[4]) | ((unsigned)f2b(xv[5]) << 16);
    o.w = (unsigned)f2b(xv[6]) | ((unsigned)f2b(xv[7]) << 16);
    *(uint4*)&curb[idx * 8] = o;
}

// ---------------- epilogue ----------------
__global__ __launch_bounds__(1024) void k_softmax(const float4* __restrict__ scores4,
                                                  const float* __restrict__ scores,
                                                  float* __restrict__ sm,
                                                  float* __restrict__ vbuf, float* __restrict__ pooled) {
    __shared__ float red[16];
    int tid = threadIdx.x, lane = tid & 63, wv = tid >> 6;
    if (tid < 128) vbuf[tid] = 0.f;
    if (tid < DINC) pooled[tid] = 0.f;
    float m = -1e30f;
    for (int i = tid; i < N_NODES / 4; i += 1024) {
        float4 s4 = scores4[i];
        m = fmaxf(fmaxf(fmaxf(m, s4.x), fmaxf(s4.y, s4.z)), s4.w);
    }
#pragma unroll
    for (int off = 32; off; off >>= 1) m = fmaxf(m, __shfl_xor(m, off));
    if (lane == 0) red[wv] = m;
    __syncthreads();
    float mall = red[0];
    for (int i = 1; i < 16; ++i) mall = fmaxf(mall, red[i]);
    __syncthreads();
    float s = 0.f;
    for (int i = tid; i < N_NODES / 4; i += 1024) {
        float4 s4 = scores4[i];
        s += __expf(s4.x - mall) + __expf(s4.y - mall) + __expf(s4.z - mall) + __expf(s4.w - mall);
    }
#pragma unroll
    for (int off = 32; off; off >>= 1) s += __shfl_xor(s, off);
    if (lane == 0) red[wv] = s;
    __syncthreads();
    if (tid == 0) {
        float tot = 0.f;
        for (int i = 0; i < 16; ++i) tot += red[i];
        sm[0] = mall; sm[1] = tot;
    }
}

__global__ __launch_bounds__(384) void k_vpool(const float* __restrict__ Fb,
                                               const unsigned short* __restrict__ hb,
                                               const float* __restrict__ scores,
                                               const float* __restrict__ sm,
                                               float* __restrict__ v,
                                               float* __restrict__ pooled) {
    int tid = threadIdx.x;
    int row0 = blockIdx.x * 64;
    float mall = sm[0];
    float invS = 1.f / sm[1];
    if (tid < 128) {
        float acc = 0.f;
        for (int r = row0; r < row0 + 64; ++r) {
            float w = __expf(scores[r] - mall) * invS;
            acc += w * Fb[(size_t)r * 128 + tid];
        }
        atomicAdd(&v[tid], acc);
    } else {
        int c = (tid - 128) * 2;
        float a0 = 0.f, a1 = 0.f;
        for (int r = row0; r < row0 + 64; ++r) {
            unsigned int hv = *(const unsigned int*)&hb[(size_t)r * DINC + c];
            a0 += lo16(hv); a1 += hi16(hv);
        }
        atomicAdd(&pooled[c], a0 * (1.f / N_NODES));
        atomicAdd(&pooled[c + 1], a1 * (1.f / N_NODES));
    }
}

__global__ __launch_bounds__(128) void k_final(const float* __restrict__ v,
                                               const float* __restrict__ pooled,
                                               const float* __restrict__ Wf2,
                                               const float* __restrict__ bf2,
                                               const float* __restrict__ Wp,
                                               const float* __restrict__ bp,
                                               float* __restrict__ out) {
    __shared__ float sg[128];
    int o = threadIdx.x;
    float g = bf2[o];
    for (int k = 0; k < 128; ++k) g += v[k] * Wf2[k * 128 + o];
    sg[o] = g;
    __syncthreads();
    float acc = bp[o];
    for (int c = 0; c < 128; ++c) acc += sg[c] * Wp[c * 128 + o];
    for (int j = 0; j < 512; ++j) acc += pooled[j] * Wp[(128 + j) * 128 + o];
    out[o] = acc;
}

// ---------------- host launch ----------------
extern "C" void kernel_launch(void* const* d_in, const int* in_sizes, int n_in,
                              void* d_out, int out_size, void* d_ws, size_t ws_size,
                              hipStream_t stream) {
    const float* x  = (const float*)d_in[0];
    const int*   ei = (const int*)d_in[1];
    const float* Wg1 = (const float*)d_in[20];
    const float* bg1 = (const float*)d_in[21];
    const float* Wg2 = (const float*)d_in[22];
    const float* bg2 = (const float*)d_in[23];
    const float* Wf1 = (const float*)d_in[24];
    const float* bf1 = (const float*)d_in[25];
    const float* Wf2 = (const float*)d_in[26];
    const float* bf2 = (const float*)d_in[27];
    const float* Wp  = (const float*)d_in[28];
    const float* bp  = (const float*)d_in[29];
    float* out = (float*)d_out;

    char* base = (char*)d_ws;
    size_t off = 0;
    auto take = [&](size_t nbytes) -> char* {
        char* p = base + off;
        off += (nbytes + 255) & ~(size_t)255;
        return p;
    };
    unsigned short* hb   = (unsigned short*)take((size_t)M_PAD * DINC * 2);
    unsigned short* curb = (unsigned short*)take((size_t)M_PAD * DINC * 2);
    unsigned short* xb   = (unsigned short*)take((size_t)M_PAD * DINC * 2);
    unsigned short* aggb = (unsigned short*)take((size_t)M_PAD * DINC * 2);
    float* Fb    = (float*)take((size_t)M_PAD * 128 * 4);
    float* es    = (float*)take((size_t)M_PAD * NHEAD * 4);
    float* ed    = (float*)take((size_t)M_PAD * NHEAD * 4);
    uint2* wbuf  = (uint2*)take((size_t)ETOT * 8);
    float* invp  = (float*)take((size_t)N_NODES * NHEAD * 4);
    int*   rowptr= (int*)take((size_t)(N_NODES + 1) * 4);
    int*   cnt   = (int*)take((size_t)N_NODES * 4);
    int*   csr   = (int*)take((size_t)ETOT * 4);
    int*   bsum  = (int*)take(625 * 4);
    float* stats = (float*)take(DINC * 2 * 4);
    float* sm    = (float*)take(2 * 4);
    float* vbuf  = (float*)take(128 * 4);
    float* pooled= (float*)take(DINC * 4);
    unsigned short* Wt1  = (unsigned short*)take((size_t)DINC * DINC * 2);
    unsigned short* Wt2  = (unsigned short*)take((size_t)DINC * DINC * 2);
    unsigned short* Wt3  = (unsigned short*)take((size_t)DINC * DINC * 2);
    unsigned short* Wct  = (unsigned short*)take((size_t)256 * DINC * 2);

    // prep (x-cvt, pads, cnt-zero, all weight transposes) + CSR build
    k_prep<<<PREP_CVTW0 + 3584, 256, 0, stream>>>((const float4*)x, (uint4*)xb,
                                                  (uint4*)curb, (uint4*)cnt,
                                                  (const float*)d_in[2], Wt1,
                                                  (const float*)d_in[8], Wt2,
                                                  (const float*)d_in[14], Wt3,
                                                  Wg1, Wf1, Wct);
    k_degree<<<(ETOT + 255) / 256, 256, 0, stream>>>(ei, cnt);
    k_scan1<<<625, 64, 0, stream>>>(cnt, bsum);
    k_scan23<<<625, 64, 0, stream>>>(cnt, bsum, rowptr, cnt);
    k_fill<<<(ETOT + 255) / 256, 256, 0, stream>>>(ei, rowptr, cnt, csr);

    const unsigned short* Wts[3] = {Wt1, Wt2, Wt3};
    const unsigned short* in = xb;
    for (int l = 0; l < 3; ++l) {
        const float* as_ = (const float*)d_in[2 + l * 6 + 1];
        const float* ad_ = (const float*)d_in[2 + l * 6 + 2];
        const float* g   = (const float*)d_in[2 + l * 6 + 4];
        const float* be  = (const float*)d_in[2 + l * 6 + 5];

        k_gemm_mfma<1, 1><<<(M_PAD / 128) * (DINC / 128), 256, 0, stream>>>(
            in, Wts[l], hb, DINC, DINC, DINC / 128, as_, ad_, es, ed, nullptr, nullptr);
        k_wts<<<N_NODES / 4, 256, 0, stream>>>((const float4*)es, (const float4*)ed, rowptr, csr,
                                               wbuf, (float4*)invp, stats);
        k_agg<<<N_NODES, 256, 0, stream>>>(hb, rowptr, csr, (const unsigned*)wbuf, invp, aggb);
        k_bn_stats<<<N_NODES / 64, 256, 0, stream>>>(aggb, stats);
        k_bn_act<<<(N_NODES * (DINC / 8)) / 256, 256, 0, stream>>>(aggb, stats, g, be, curb, l > 0 ? 1 : 0);
        in = curb;
    }

    // fused epilogue GEMM: [M,512] @ [512,256]; G half -> scores, F half -> relu F
    float* scores = out + 128;
    k_gemm_mfma<0, 2><<<(M_PAD / 128) * 2, 256, 0, stream>>>(
        curb, Wct, nullptr, 256, DINC, 2, bg1, Wg2, scores, Fb, bg2, bf1);

    k_softmax<<<1, 1024, 0, stream>>>((const float4*)scores, scores, sm, vbuf, pooled);
    k_vpool<<<N_NODES / 64, 384, 0, stream>>>(Fb, curb, scores, sm, vbuf, pooled);
    k_final<<<1, 128, 0, stream>>>(vbuf, pooled, Wf2, bf2, Wp, bp, out);
}